// Round 5
// baseline (5625.602 us; speedup 1.0000x reference)
//
#include <hip/hip_runtime.h>
#include <math.h>

#define TM 64
#define TN 64
#define TK 16
#define MCHUNK 4

// Tiled GEMM, chunked accumulation: fp32 within each TK=16 K-chunk, fp64
// across chunks. Arg error ~2e-5 << np reference's own fp32 error (~3e-4),
// so numerically equivalent to full-fp64 for the test, at ~fp32 speed.
// (The tanh args are chaotic: std ~1000, saturating tanh feeding a sharp
// softmax — plain fp32 sequential accumulation loses by absmax 0.16.)
template<bool TRANS_B, bool TANH>
__global__ __launch_bounds__(256)
void gemm_kernel(const float* __restrict__ A, const float* __restrict__ B,
                 float* __restrict__ C,
                 int M, int N, int K,
                 long sA, long sB, long sC,
                 int lda, int ldb, int ldc)
{
    __shared__ float As[TK][TM + 1];
    __shared__ float Bs[TK][TN + 1];
    const int tid = threadIdx.x;
    const int tx = tid & 15;   // n
    const int ty = tid >> 4;   // m
    const int bz = blockIdx.z;
    const float* Ab = A + (long)bz * sA;
    const float* Bb = B + (long)bz * sB;
    float* Cb = C + (long)bz * sC;
    const int m0 = blockIdx.y * TM;
    const int n0 = blockIdx.x * TN;

    double acc[4][4];
#pragma unroll
    for (int i = 0; i < 4; ++i)
#pragma unroll
        for (int j = 0; j < 4; ++j) acc[i][j] = 0.0;

    const int ktiles = (K + TK - 1) / TK;
    for (int kt = 0; kt < ktiles; ++kt) {
        const int k0 = kt * TK;
        {   // A tile 64x16, A row-major [M x K]
            int k = tid & 15, mrel = tid >> 4;
#pragma unroll
            for (int r = 0; r < 4; ++r) {
                int m = mrel + r * 16;
                float v = 0.f;
                if (m0 + m < M && k0 + k < K) v = Ab[(long)(m0 + m) * lda + (k0 + k)];
                As[k][m] = v;
            }
        }
        if (!TRANS_B) {  // B row-major [K x N]
            int n = tid & 63, krel = tid >> 6;
#pragma unroll
            for (int r = 0; r < 4; ++r) {
                int k = krel + r * 4;
                float v = 0.f;
                if (k0 + k < K && n0 + n < N) v = Bb[(long)(k0 + k) * ldb + (n0 + n)];
                Bs[k][n] = v;
            }
        } else {         // B[k,n] = Bt[n,k], Bt row-major [N x K]
            int k = tid & 15, nrel = tid >> 4;
#pragma unroll
            for (int r = 0; r < 4; ++r) {
                int n = nrel + r * 16;
                float v = 0.f;
                if (n0 + n < N && k0 + k < K) v = Bb[(long)(n0 + n) * ldb + (k0 + k)];
                Bs[k][n] = v;
            }
        }
        __syncthreads();
        float facc[4][4];
#pragma unroll
        for (int i = 0; i < 4; ++i)
#pragma unroll
            for (int j = 0; j < 4; ++j) facc[i][j] = 0.f;
#pragma unroll
        for (int kk = 0; kk < TK; ++kk) {
            float a[4], bb[4];
#pragma unroll
            for (int i = 0; i < 4; ++i) a[i] = As[kk][ty + 16 * i];
#pragma unroll
            for (int j = 0; j < 4; ++j) bb[j] = Bs[kk][tx + 16 * j];
#pragma unroll
            for (int i = 0; i < 4; ++i)
#pragma unroll
                for (int j = 0; j < 4; ++j)
                    facc[i][j] = fmaf(a[i], bb[j], facc[i][j]);
        }
#pragma unroll
        for (int i = 0; i < 4; ++i)
#pragma unroll
            for (int j = 0; j < 4; ++j) acc[i][j] += (double)facc[i][j];
        __syncthreads();
    }
#pragma unroll
    for (int i = 0; i < 4; ++i) {
        int m = m0 + ty + 16 * i;
        if (m >= M) continue;
#pragma unroll
        for (int j = 0; j < 4; ++j) {
            int n = n0 + tx + 16 * j;
            if (n >= N) continue;
            float v = (float)acc[i][j];
            if (TANH) v = tanhf(v);
            Cb[(long)m * ldc + n] = v;
        }
    }
}

// Fused: s[b,n] += sum_m w[m] * tanh( bias[b,m,n] + sum_k A[b,m,k]*B[b,k,n] )
// H_v / H_q never materialized. Same chunked fp32/fp64 accumulation.
template<bool TRANS_B>
__global__ __launch_bounds__(256)
void score_kernel(const float* __restrict__ A, const float* __restrict__ B,
                  const float* __restrict__ bias, const float* __restrict__ w,
                  float* __restrict__ s,
                  int M, int N, int K,
                  long sA, long sB, long sBias,
                  int lda, int ldb, int ldbias)
{
    __shared__ float As[TK][TM + 1];
    __shared__ float Bs[TK][TN + 1];
    __shared__ float red[16][TN];
    const int tid = threadIdx.x;
    const int tx = tid & 15;
    const int ty = tid >> 4;
    const int bz = blockIdx.z;
    const float* Ab = A + (long)bz * sA;
    const float* Bb = B + (long)bz * sB;
    const float* biasb = bias + (long)bz * sBias;
    const int n0 = blockIdx.x * TN;
    const int ktiles = (K + TK - 1) / TK;

    float sacc[4] = {0.f, 0.f, 0.f, 0.f};

    for (int mt = 0; mt < MCHUNK; ++mt) {
        const int m0 = (blockIdx.y * MCHUNK + mt) * TM;
        if (m0 >= M) break;
        double acc[4][4];
#pragma unroll
        for (int i = 0; i < 4; ++i)
#pragma unroll
            for (int j = 0; j < 4; ++j) acc[i][j] = 0.0;

        for (int kt = 0; kt < ktiles; ++kt) {
            const int k0 = kt * TK;
            {
                int k = tid & 15, mrel = tid >> 4;
#pragma unroll
                for (int r = 0; r < 4; ++r) {
                    int m = mrel + r * 16;
                    float v = 0.f;
                    if (m0 + m < M && k0 + k < K) v = Ab[(long)(m0 + m) * lda + (k0 + k)];
                    As[k][m] = v;
                }
            }
            if (!TRANS_B) {
                int n = tid & 63, krel = tid >> 6;
#pragma unroll
                for (int r = 0; r < 4; ++r) {
                    int k = krel + r * 4;
                    float v = 0.f;
                    if (k0 + k < K && n0 + n < N) v = Bb[(long)(k0 + k) * ldb + (n0 + n)];
                    Bs[k][n] = v;
                }
            } else {
                int k = tid & 15, nrel = tid >> 4;
#pragma unroll
                for (int r = 0; r < 4; ++r) {
                    int n = nrel + r * 16;
                    float v = 0.f;
                    if (n0 + n < N && k0 + k < K) v = Bb[(long)(n0 + n) * ldb + (k0 + k)];
                    Bs[k][n] = v;
                }
            }
            __syncthreads();
            float facc[4][4];
#pragma unroll
            for (int i = 0; i < 4; ++i)
#pragma unroll
                for (int j = 0; j < 4; ++j) facc[i][j] = 0.f;
#pragma unroll
            for (int kk = 0; kk < TK; ++kk) {
                float a[4], bb[4];
#pragma unroll
                for (int i = 0; i < 4; ++i) a[i] = As[kk][ty + 16 * i];
#pragma unroll
                for (int j = 0; j < 4; ++j) bb[j] = Bs[kk][tx + 16 * j];
#pragma unroll
                for (int i = 0; i < 4; ++i)
#pragma unroll
                    for (int j = 0; j < 4; ++j)
                        facc[i][j] = fmaf(a[i], bb[j], facc[i][j]);
            }
#pragma unroll
            for (int i = 0; i < 4; ++i)
#pragma unroll
                for (int j = 0; j < 4; ++j) acc[i][j] += (double)facc[i][j];
            __syncthreads();
        }
        // epilogue: bias + tanh + w-weighted reduction over m
#pragma unroll
        for (int i = 0; i < 4; ++i) {
            int m = m0 + ty + 16 * i;
            if (m >= M) continue;
            float wm = w[m];
#pragma unroll
            for (int j = 0; j < 4; ++j) {
                int n = n0 + tx + 16 * j;
                if (n >= N) continue;
                float t = tanhf((float)(acc[i][j] + (double)biasb[(long)m * ldbias + n]));
                sacc[j] = fmaf(wm, t, sacc[j]);
            }
        }
    }
    // reduce sacc over the 16 ty-threads sharing each n
#pragma unroll
    for (int j = 0; j < 4; ++j) red[ty][tx + 16 * j] = sacc[j];
    __syncthreads();
    if (tid < TN) {
        float tot = 0.f;
#pragma unroll
        for (int t = 0; t < 16; ++t) tot += red[t][tid];
        int n = n0 + tid;
        if (n < N) atomicAdd(&s[(long)bz * N + n], tot);
    }
}

// softmax(s[b,:]) then out[b,d] = sum_v a[v] * X[b,v,d]
__global__ __launch_bounds__(256)
void softmax_wsum(const float* __restrict__ s, const float* __restrict__ X,
                  float* __restrict__ out, int N, int D)
{
    const int b = blockIdx.x;
    __shared__ float a[512];
    __shared__ float wred[4];
    const int tid = threadIdx.x;
    const float* sb = s + (long)b * N;

    float lm = -1e30f;
    for (int i = tid; i < N; i += 256) lm = fmaxf(lm, sb[i]);
#pragma unroll
    for (int o = 32; o; o >>= 1) lm = fmaxf(lm, __shfl_down(lm, o, 64));
    if ((tid & 63) == 0) wred[tid >> 6] = lm;
    __syncthreads();
    float gm = fmaxf(fmaxf(wred[0], wred[1]), fmaxf(wred[2], wred[3]));
    __syncthreads();

    float ls = 0.f;
    for (int i = tid; i < N; i += 256) {
        float e = expf(sb[i] - gm);
        a[i] = e;
        ls += e;
    }
#pragma unroll
    for (int o = 32; o; o >>= 1) ls += __shfl_down(ls, o, 64);
    if ((tid & 63) == 0) wred[tid >> 6] = ls;
    __syncthreads();
    float inv = 1.f / (wred[0] + wred[1] + wred[2] + wred[3]);
    for (int i = tid; i < N; i += 256) a[i] *= inv;
    __syncthreads();

    int d = blockIdx.y * 256 + tid;
    const float* Xb = X + (long)b * N * D;
    float acc = 0.f;
    for (int v = 0; v < N; ++v) acc = fmaf(a[v], Xb[(long)v * D + d], acc);
    out[(long)b * D + d] = acc;
}

extern "C" void kernel_launch(void* const* d_in, const int* in_sizes, int n_in,
                              void* d_out, int out_size, void* d_ws, size_t ws_size,
                              hipStream_t stream)
{
    const float* V    = (const float*)d_in[0];
    const float* Q    = (const float*)d_in[1];
    const float* W_b  = (const float*)d_in[2];
    const float* W_v  = (const float*)d_in[3];
    const float* W_q  = (const float*)d_in[4];
    const float* w_hv = (const float*)d_in[5];
    const float* w_hq = (const float*)d_in[6];
    float* out = (float*)d_out;

    const int B = 64, NV = 196, NQ = 512, D = 1024;

    float* ws  = (float*)d_ws;
    float* QW  = ws;                          // B*NQ*D   = 33,554,432 f
    float* Cb  = QW  + (long)B * NQ * D;      // B*NQ*NV  =  6,422,528 f
    float* WvV = Cb  + (long)B * NQ * NV;     // B*D*NV   = 12,845,056 f
    float* WqQ = WvV + (long)B * D * NV;      // B*D*NQ   = 33,554,432 f
    float* s_v = WqQ + (long)B * D * NQ;      // B*NV
    float* s_q = s_v + (long)B * NV;          // B*NQ

    hipMemsetAsync(s_v, 0, (size_t)(B * NV + B * NQ) * sizeof(float), stream);

    // 1. QW = Q @ W_b   (flattened: [B*NQ, D] x [D, D])
    gemm_kernel<false, false><<<dim3(D / 64, (B * NQ) / 64, 1), 256, 0, stream>>>(
        Q, W_b, QW, B * NQ, D, D, 0, 0, 0, D, D, D);

    // 2. C = tanh(QW[b] @ V[b]^T)   [NQ x NV]
    gemm_kernel<true, true><<<dim3((NV + 63) / 64, NQ / 64, B), 256, 0, stream>>>(
        QW, V, Cb, NQ, NV, D, (long)NQ * D, (long)NV * D, (long)NQ * NV, D, D, NV);

    // 3. WvV[b] = W_v @ V[b]^T   [D x NV]
    gemm_kernel<true, false><<<dim3((NV + 63) / 64, D / 64, B), 256, 0, stream>>>(
        W_v, V, WvV, D, NV, D, 0, (long)NV * D, (long)D * NV, D, D, NV);

    // 4. WqQ[b] = W_q @ Q[b]^T   [D x NQ]
    gemm_kernel<true, false><<<dim3(NQ / 64, D / 64, B), 256, 0, stream>>>(
        W_q, Q, WqQ, D, NQ, D, 0, (long)NQ * D, (long)D * NQ, D, D, NQ);

    // 5. s_v[b,v] = sum_d w_hv[d] * tanh(WvV[b,d,v] + sum_q WqQ[b,d,q]*C[b,q,v])
    score_kernel<false><<<dim3((NV + 63) / 64, 4, B), 256, 0, stream>>>(
        WqQ, Cb, WvV, w_hv, s_v, D, NV, NQ,
        (long)D * NQ, (long)NQ * NV, (long)D * NV, NQ, NV, NV);

    // 6. s_q[b,q] = sum_d w_hq[d] * tanh(WqQ[b,d,q] + sum_v WvV[b,d,v]*C[b,q,v])
    score_kernel<true><<<dim3(NQ / 64, 4, B), 256, 0, stream>>>(
        WvV, Cb, WqQ, w_hq, s_q, D, NQ, NV,
        (long)D * NV, (long)NQ * NV, (long)D * NQ, NV, NV, NQ);

    // 7. v_hat = softmax(s_v) @ V
    softmax_wsum<<<dim3(B, D / 256), 256, 0, stream>>>(s_v, V, out, NV, D);

    // 8. q_hat = softmax(s_q) @ Q
    softmax_wsum<<<dim3(B, D / 256), 256, 0, stream>>>(s_q, Q, out + (long)B * D, NQ, D);
}

// Round 13
// 3471.998 us; speedup vs baseline: 1.6203x; 1.6203x over previous
//
#include <hip/hip_runtime.h>
#include <math.h>

#define TM 64
#define TN 64
#define TK 16
#define MCHUNK 4
#define LDSP 68   // padded row stride (words): 16B-aligned, low bank aliasing

// Tiled GEMM, chunked accumulation: fp32 within each TK=16 K-chunk, fp64
// across chunks (numerics frozen — passing config, absmax 0.0747/0.0875).
// Contiguous 4x4 microtile: a/b fragments are single ds_read_b128 each.
template<bool TRANS_B, bool TANH>
__global__ __launch_bounds__(256)
void gemm_kernel(const float* __restrict__ A, const float* __restrict__ B,
                 float* __restrict__ C,
                 int M, int N, int K,
                 long sA, long sB, long sC,
                 int lda, int ldb, int ldc)
{
    __shared__ float As[TK][LDSP];
    __shared__ float Bs[TK][LDSP];
    const int tid = threadIdx.x;
    const int tx = tid & 15;   // n-group
    const int ty = tid >> 4;   // m-group
    const int bz = blockIdx.z;
    const float* Ab = A + (long)bz * sA;
    const float* Bb = B + (long)bz * sB;
    float* Cb = C + (long)bz * sC;
    const int m0 = blockIdx.y * TM;
    const int n0 = blockIdx.x * TN;

    double acc[4][4];
#pragma unroll
    for (int i = 0; i < 4; ++i)
#pragma unroll
        for (int j = 0; j < 4; ++j) acc[i][j] = 0.0;

    const int ktiles = (K + TK - 1) / TK;
    for (int kt = 0; kt < ktiles; ++kt) {
        const int k0 = kt * TK;
        {   // A tile 64x16: one float4 along k per thread
            int m = tid >> 2, kg = (tid & 3) * 4;
            float4 v = make_float4(0.f, 0.f, 0.f, 0.f);
            if (m0 + m < M && k0 + kg < K)
                v = *(const float4*)&Ab[(long)(m0 + m) * lda + (k0 + kg)];
            As[kg + 0][m] = v.x; As[kg + 1][m] = v.y;
            As[kg + 2][m] = v.z; As[kg + 3][m] = v.w;
        }
        if (!TRANS_B) {  // B row-major [K x N]: float4 along n
            int k = tid >> 4, c = (tid & 15) * 4;
            float4 v = make_float4(0.f, 0.f, 0.f, 0.f);
            if (n0 + c < N)   // N%4==0 in all uses -> all-or-nothing
                v = *(const float4*)&Bb[(long)(k0 + k) * ldb + (n0 + c)];
            *(float4*)&Bs[k][c] = v;
        } else {         // B[k,n] = Bt[n,k], Bt row-major [N x K]: float4 along k
            int n = tid >> 2, kg = (tid & 3) * 4;
            float4 v = make_float4(0.f, 0.f, 0.f, 0.f);
            if (n0 + n < N && k0 + kg < K)
                v = *(const float4*)&Bb[(long)(n0 + n) * ldb + (k0 + kg)];
            Bs[kg + 0][n] = v.x; Bs[kg + 1][n] = v.y;
            Bs[kg + 2][n] = v.z; Bs[kg + 3][n] = v.w;
        }
        __syncthreads();
        float facc[4][4];
#pragma unroll
        for (int i = 0; i < 4; ++i)
#pragma unroll
            for (int j = 0; j < 4; ++j) facc[i][j] = 0.f;
#pragma unroll
        for (int kk = 0; kk < TK; ++kk) {
            float4 a = *(const float4*)&As[kk][ty * 4];
            float4 b = *(const float4*)&Bs[kk][tx * 4];
            float av[4] = {a.x, a.y, a.z, a.w};
            float bv[4] = {b.x, b.y, b.z, b.w};
#pragma unroll
            for (int i = 0; i < 4; ++i)
#pragma unroll
                for (int j = 0; j < 4; ++j)
                    facc[i][j] = fmaf(av[i], bv[j], facc[i][j]);
        }
#pragma unroll
        for (int i = 0; i < 4; ++i)
#pragma unroll
            for (int j = 0; j < 4; ++j) acc[i][j] += (double)facc[i][j];
        __syncthreads();
    }
#pragma unroll
    for (int i = 0; i < 4; ++i) {
        int m = m0 + ty * 4 + i;
        if (m >= M) continue;
        int n = n0 + tx * 4;
        if (n >= N) continue;   // N%4==0 -> all-or-nothing
        float4 v;
        v.x = (float)acc[i][0]; v.y = (float)acc[i][1];
        v.z = (float)acc[i][2]; v.w = (float)acc[i][3];
        if (TANH) {
            v.x = tanhf(v.x); v.y = tanhf(v.y);
            v.z = tanhf(v.z); v.w = tanhf(v.w);
        }
        *(float4*)&Cb[(long)m * ldc + n] = v;
    }
}

// Fused: s[b,n] += sum_m w[m] * tanh( bias[b,m,n] + sum_k A[b,m,k]*B[b,k,n] )
// H_v / H_q never materialized. Same chunked fp32/fp64 accumulation.
template<bool TRANS_B>
__global__ __launch_bounds__(256)
void score_kernel(const float* __restrict__ A, const float* __restrict__ B,
                  const float* __restrict__ bias, const float* __restrict__ w,
                  float* __restrict__ s,
                  int M, int N, int K,
                  long sA, long sB, long sBias,
                  int lda, int ldb, int ldbias)
{
    __shared__ float As[TK][LDSP];
    __shared__ float Bs[TK][LDSP];
    __shared__ float red[16][TN];
    const int tid = threadIdx.x;
    const int tx = tid & 15;
    const int ty = tid >> 4;
    const int bz = blockIdx.z;
    const float* Ab = A + (long)bz * sA;
    const float* Bb = B + (long)bz * sB;
    const float* biasb = bias + (long)bz * sBias;
    const int n0 = blockIdx.x * TN;
    const int ktiles = (K + TK - 1) / TK;

    float sacc[4] = {0.f, 0.f, 0.f, 0.f};

    for (int mt = 0; mt < MCHUNK; ++mt) {
        const int m0 = (blockIdx.y * MCHUNK + mt) * TM;
        if (m0 >= M) break;
        double acc[4][4];
#pragma unroll
        for (int i = 0; i < 4; ++i)
#pragma unroll
            for (int j = 0; j < 4; ++j) acc[i][j] = 0.0;

        for (int kt = 0; kt < ktiles; ++kt) {
            const int k0 = kt * TK;
            {   // A tile: float4 along k
                int m = tid >> 2, kg = (tid & 3) * 4;
                float4 v = make_float4(0.f, 0.f, 0.f, 0.f);
                if (m0 + m < M && k0 + kg < K)   // K%4==0 (512/196)
                    v = *(const float4*)&Ab[(long)(m0 + m) * lda + (k0 + kg)];
                As[kg + 0][m] = v.x; As[kg + 1][m] = v.y;
                As[kg + 2][m] = v.z; As[kg + 3][m] = v.w;
            }
            if (!TRANS_B) {
                int k = tid >> 4, c = (tid & 15) * 4;
                float4 v = make_float4(0.f, 0.f, 0.f, 0.f);
                if (k0 + k < K && n0 + c < N)
                    v = *(const float4*)&Bb[(long)(k0 + k) * ldb + (n0 + c)];
                *(float4*)&Bs[k][c] = v;
            } else {
                int n = tid >> 2, kg = (tid & 3) * 4;
                float4 v = make_float4(0.f, 0.f, 0.f, 0.f);
                if (n0 + n < N && k0 + kg < K)
                    v = *(const float4*)&Bb[(long)(n0 + n) * ldb + (k0 + kg)];
                Bs[kg + 0][n] = v.x; Bs[kg + 1][n] = v.y;
                Bs[kg + 2][n] = v.z; Bs[kg + 3][n] = v.w;
            }
            __syncthreads();
            float facc[4][4];
#pragma unroll
            for (int i = 0; i < 4; ++i)
#pragma unroll
                for (int j = 0; j < 4; ++j) facc[i][j] = 0.f;
#pragma unroll
            for (int kk = 0; kk < TK; ++kk) {
                float4 a = *(const float4*)&As[kk][ty * 4];
                float4 b = *(const float4*)&Bs[kk][tx * 4];
                float av[4] = {a.x, a.y, a.z, a.w};
                float bv[4] = {b.x, b.y, b.z, b.w};
#pragma unroll
                for (int i = 0; i < 4; ++i)
#pragma unroll
                    for (int j = 0; j < 4; ++j)
                        facc[i][j] = fmaf(av[i], bv[j], facc[i][j]);
            }
#pragma unroll
            for (int i = 0; i < 4; ++i)
#pragma unroll
                for (int j = 0; j < 4; ++j) acc[i][j] += (double)facc[i][j];
            __syncthreads();
        }
        // epilogue: bias + tanh + w-weighted reduction over m
#pragma unroll
        for (int i = 0; i < 4; ++i) {
            int m = m0 + ty * 4 + i;
            if (m >= M) continue;
            float wm = w[m];
#pragma unroll
            for (int j = 0; j < 4; ++j) {
                int n = n0 + tx * 4 + j;
                if (n >= N) continue;
                float t = tanhf((float)(acc[i][j] + (double)biasb[(long)m * ldbias + n]));
                sacc[j] = fmaf(wm, t, sacc[j]);
            }
        }
    }
    // reduce sacc over the 16 ty-threads sharing each n
#pragma unroll
    for (int j = 0; j < 4; ++j) red[ty][tx * 4 + j] = sacc[j];
    __syncthreads();
    if (tid < TN) {
        float tot = 0.f;
#pragma unroll
        for (int t = 0; t < 16; ++t) tot += red[t][tid];
        int n = n0 + tid;
        if (n < N) atomicAdd(&s[(long)bz * N + n], tot);
    }
}

// softmax(s[b,:]) then out[b,d] = sum_v a[v] * X[b,v,d]
__global__ __launch_bounds__(256)
void softmax_wsum(const float* __restrict__ s, const float* __restrict__ X,
                  float* __restrict__ out, int N, int D)
{
    const int b = blockIdx.x;
    __shared__ float a[512];
    __shared__ float wred[4];
    const int tid = threadIdx.x;
    const float* sb = s + (long)b * N;

    float lm = -1e30f;
    for (int i = tid; i < N; i += 256) lm = fmaxf(lm, sb[i]);
#pragma unroll
    for (int o = 32; o; o >>= 1) lm = fmaxf(lm, __shfl_down(lm, o, 64));
    if ((tid & 63) == 0) wred[tid >> 6] = lm;
    __syncthreads();
    float gm = fmaxf(fmaxf(wred[0], wred[1]), fmaxf(wred[2], wred[3]));
    __syncthreads();

    float ls = 0.f;
    for (int i = tid; i < N; i += 256) {
        float e = expf(sb[i] - gm);
        a[i] = e;
        ls += e;
    }
#pragma unroll
    for (int o = 32; o; o >>= 1) ls += __shfl_down(ls, o, 64);
    if ((tid & 63) == 0) wred[tid >> 6] = ls;
    __syncthreads();
    float inv = 1.f / (wred[0] + wred[1] + wred[2] + wred[3]);
    for (int i = tid; i < N; i += 256) a[i] *= inv;
    __syncthreads();

    int d = blockIdx.y * 256 + tid;
    const float* Xb = X + (long)b * N * D;
    float acc = 0.f;
    for (int v = 0; v < N; ++v) acc = fmaf(a[v], Xb[(long)v * D + d], acc);
    out[(long)b * D + d] = acc;
}

extern "C" void kernel_launch(void* const* d_in, const int* in_sizes, int n_in,
                              void* d_out, int out_size, void* d_ws, size_t ws_size,
                              hipStream_t stream)
{
    const float* V    = (const float*)d_in[0];
    const float* Q    = (const float*)d_in[1];
    const float* W_b  = (const float*)d_in[2];
    const float* W_v  = (const float*)d_in[3];
    const float* W_q  = (const float*)d_in[4];
    const float* w_hv = (const float*)d_in[5];
    const float* w_hq = (const float*)d_in[6];
    float* out = (float*)d_out;

    const int B = 64, NV = 196, NQ = 512, D = 1024;

    float* ws  = (float*)d_ws;
    float* QW  = ws;                          // B*NQ*D   = 33,554,432 f
    float* Cb  = QW  + (long)B * NQ * D;      // B*NQ*NV  =  6,422,528 f
    float* WvV = Cb  + (long)B * NQ * NV;     // B*D*NV   = 12,845,056 f
    float* WqQ = WvV + (long)B * D * NV;     // B*D*NQ   = 33,554,432 f
    float* s_v = WqQ + (long)B * D * NQ;      // B*NV
    float* s_q = s_v + (long)B * NV;          // B*NQ

    hipMemsetAsync(s_v, 0, (size_t)(B * NV + B * NQ) * sizeof(float), stream);

    // 1. QW = Q @ W_b   (flattened: [B*NQ, D] x [D, D])
    gemm_kernel<false, false><<<dim3(D / 64, (B * NQ) / 64, 1), 256, 0, stream>>>(
        Q, W_b, QW, B * NQ, D, D, 0, 0, 0, D, D, D);

    // 2. C = tanh(QW[b] @ V[b]^T)   [NQ x NV]
    gemm_kernel<true, true><<<dim3((NV + 63) / 64, NQ / 64, B), 256, 0, stream>>>(
        QW, V, Cb, NQ, NV, D, (long)NQ * D, (long)NV * D, (long)NQ * NV, D, D, NV);

    // 3. WvV[b] = W_v @ V[b]^T   [D x NV]
    gemm_kernel<true, false><<<dim3((NV + 63) / 64, D / 64, B), 256, 0, stream>>>(
        W_v, V, WvV, D, NV, D, 0, (long)NV * D, (long)D * NV, D, D, NV);

    // 4. WqQ[b] = W_q @ Q[b]^T   [D x NQ]
    gemm_kernel<true, false><<<dim3(NQ / 64, D / 64, B), 256, 0, stream>>>(
        W_q, Q, WqQ, D, NQ, D, 0, (long)NQ * D, (long)D * NQ, D, D, NQ);

    // 5. s_v[b,v] = sum_d w_hv[d] * tanh(WvV[b,d,v] + sum_q WqQ[b,d,q]*C[b,q,v])
    score_kernel<false><<<dim3((NV + 63) / 64, 4, B), 256, 0, stream>>>(
        WqQ, Cb, WvV, w_hv, s_v, D, NV, NQ,
        (long)D * NQ, (long)NQ * NV, (long)D * NV, NQ, NV, NV);

    // 6. s_q[b,q] = sum_d w_hq[d] * tanh(WqQ[b,d,q] + sum_v WvV[b,d,v]*C[b,q,v])
    score_kernel<true><<<dim3(NQ / 64, 4, B), 256, 0, stream>>>(
        WvV, Cb, WqQ, w_hq, s_q, D, NQ, NV,
        (long)D * NV, (long)NQ * NV, (long)D * NQ, NV, NV, NQ);

    // 7. v_hat = softmax(s_v) @ V
    softmax_wsum<<<dim3(B, D / 256), 256, 0, stream>>>(s_v, V, out, NV, D);

    // 8. q_hat = softmax(s_q) @ Q
    softmax_wsum<<<dim3(B, D / 256), 256, 0, stream>>>(s_q, Q, out + (long)B * D, NQ, D);
}